// Round 9
// baseline (262.745 us; speedup 1.0000x reference)
//
#include <hip/hip_runtime.h>
#include <stdint.h>
#include <math.h>

#define DEVI __device__ __forceinline__

typedef __attribute__((ext_vector_type(8))) short bf16x8;
typedef __attribute__((ext_vector_type(4))) float f32x4;

DEVI unsigned short f2bf(float f) {
  union { float f; unsigned u; } v; v.f = f;
  unsigned u = v.u;
  u += 0x7fffu + ((u >> 16) & 1u);   // round-to-nearest-even
  return (unsigned short)(u >> 16);
}

// pack two f32 -> one dword of 2x bf16 (lo = a, hi = b), RNE; no builtin on gfx950
DEVI unsigned cvt_pk_bf16(float a, float b) {
  unsigned r;
  asm("v_cvt_pk_bf16_f32 %0, %1, %2" : "=v"(r) : "v"(a), "v"(b));
  return r;
}

DEVI f32x4 mfma16(bf16x8 a, bf16x8 b, f32x4 c) {
  return __builtin_amdgcn_mfma_f32_16x16x32_bf16(a, b, c, 0, 0, 0);
}

// async global->LDS, 16 B per lane; LDS dest = wave-uniform base + lane*16
DEVI void gld16(const unsigned short* g, unsigned short* l) {
  __builtin_amdgcn_global_load_lds(
      (const __attribute__((address_space(1))) unsigned int*)(uintptr_t)g,
      (__attribute__((address_space(3))) unsigned int*)(unsigned int)(uintptr_t)l,
      16, 0, 0);
}

#define VMCNT(n) asm volatile("s_waitcnt vmcnt(" #n ")" ::: "memory")
#define BAR()                              \
  do {                                     \
    __builtin_amdgcn_s_barrier();          \
    __builtin_amdgcn_sched_barrier(0);     \
  } while (0)

// ---------------- fp32 -> bf16 convert (3 buffers, one launch) ----------------
__global__ __launch_bounds__(256) void cvt3_kernel(
    const float* __restrict__ a, unsigned short* __restrict__ oa,
    const float* __restrict__ b, unsigned short* __restrict__ ob,
    const float* __restrict__ c, unsigned short* __restrict__ oc) {
  int bid = blockIdx.x;
  const float* in; unsigned short* out; int i;
  if (bid < 8192)       { in = a; out = oa; i = bid; }
  else if (bid < 11264) { in = b; out = ob; i = bid - 8192; }
  else                  { in = c; out = oc; i = bid - 11264; }
  int idx = (i * 256 + (int)threadIdx.x) * 4;
  float4 v = *(const float4*)(in + idx);
  unsigned lo = f2bf(v.x) | ((unsigned)f2bf(v.y) << 16);
  unsigned hi = f2bf(v.z) | ((unsigned)f2bf(v.w) << 16);
  uint2 o; o.x = lo; o.y = hi;
  *(uint2*)(out + idx) = o;
}

// ======== triple-buffered GEMM: C[M,N] = A[M,K]*Bw[N,K]^T + bias ========
// Round-9: BM=128, BN=256, BK=64, 8 waves (2M x 4N), wave tile 64x64.
// LDS = 3 x (A 16KB | B 32KB) = 144 KiB. Whole-tile staging, 2-tile prefetch
// distance: iter t issues tile t+2's loads, computes tile t with ZERO
// intra-tile gates (tile fully landed), then ONE vmcnt(6)+barrier proving
// tile t+1 landed (loads issued ~2 tiles = ~1500cy earlier -> HBM latency
// hidden). r8 post-mortem: per-block time was NT x gate-stall, independent
// of tile size (proj at half tile = same 71us) -> kill the gates.
// XOR swizzle kept (r7 lesson: 64B stride = 8-way conflict; 128B+swz = 0).
// WAR: buffer (t+2)%3 last read in iter t-1, sealed by that iter's barrier.
// MODE==0 writes Q,K as [b,h,t,d] and V TRANSPOSED as [b,h,d,t].
template <int MODE>
__global__ __launch_bounds__(512, 2) void gemm8(
    const unsigned short* __restrict__ A, const unsigned short* __restrict__ Bw,
    const float* __restrict__ bias, float* __restrict__ Cf,
    unsigned short* __restrict__ Qo, unsigned short* __restrict__ Ko,
    unsigned short* __restrict__ Vo, int M, int N, int K, int nbx) {
  extern __shared__ unsigned short lds[];   // 3 x [A 8192 | B 16384] ushorts
  constexpr int BUFS = 8192 + 16384;        // ushorts per buffer (48 KB)
  const int tid = threadIdx.x;
  const int lane = tid & 63;
  const int w = tid >> 6;                   // 0..7
  const int wm = w >> 2, wn = w & 3;
  const int lr = lane & 15, lq = lane >> 4;

  // T1: XCD-aware block swizzle (grid % 8 == 0 for both call sites)
  const int cpx = gridDim.x >> 3;
  const int swz = (blockIdx.x & 7) * cpx + (blockIdx.x >> 3);
  const int bx = swz % nbx, by = swz / nbx;
  const int m0 = by * 128, n0 = bx * 256;

  // staging source coords (swizzle baked into the per-lane global column)
  const int sr = lane >> 3;                       // 0..7 row within chunk
  const int sc = ((lane & 7) ^ sr) << 3;          // swizzled col element
  const unsigned short* pa = A + (size_t)(m0 + sr) * K + sc;
  const unsigned short* pb = Bw + (size_t)(n0 + sr) * K + sc;

  // fragment-read block swizzle offsets (ushorts); row&7 == lr&7 for all frags
  const int bs0 = (lq ^ (lr & 7)) << 3;
  const int bs1 = ((lq + 4) ^ (lr & 7)) << 3;

  f32x4 acc[4][4] = {};

  auto sA = [&](int buf, int kt, int c) {
    gld16(pa + (size_t)(c << 3) * K + kt, lds + buf * BUFS + (c << 9));
  };
  auto sB = [&](int buf, int kt, int c) {
    gld16(pb + (size_t)(c << 3) * K + kt, lds + buf * BUFS + 8192 + (c << 9));
  };
  // whole tile: A 16 chunks (2/wave), B 32 chunks (4/wave) -> 6 loads/thread
  auto stage = [&](int buf, int t) {
    const int kt = t << 6;
    sA(buf, kt, w); sA(buf, kt, 8 + w);
    sB(buf, kt, w); sB(buf, kt, 8 + w); sB(buf, kt, 16 + w); sB(buf, kt, 24 + w);
  };

// load A fragments for mh-half: 2 frags x 2 k-halves (4 ds_read_b128)
#define LDA(A_, mh)                                                          \
  _Pragma("unroll") for (int i = 0; i < 2; ++i) {                            \
    int ar = wm * 64 + (mh) * 32 + i * 16 + lr;                              \
    A_[i][0] = *(const bf16x8*)(As_ + ar * 64 + bs0);                        \
    A_[i][1] = *(const bf16x8*)(As_ + ar * 64 + bs1);                        \
  }
// load B fragments for nh-half: 2 frags x 2 k-halves (4 ds_read_b128)
#define LDB(B_, nh)                                                          \
  _Pragma("unroll") for (int j = 0; j < 2; ++j) {                            \
    int br = wn * 64 + (nh) * 32 + j * 16 + lr;                              \
    B_[j][0] = *(const bf16x8*)(Bs_ + br * 64 + bs0);                        \
    B_[j][1] = *(const bf16x8*)(Bs_ + br * 64 + bs1);                        \
  }
// one C-quadrant x K=64 from held fragments (8 MFMA)
#define MM(A_, B_, mh, nh)                                                   \
  __builtin_amdgcn_s_setprio(1);                                             \
  _Pragma("unroll") for (int i = 0; i < 2; ++i)                              \
    _Pragma("unroll") for (int j = 0; j < 2; ++j) {                          \
      acc[(mh) * 2 + i][(nh) * 2 + j] =                                      \
          mfma16(A_[i][0], B_[j][0], acc[(mh) * 2 + i][(nh) * 2 + j]);       \
      acc[(mh) * 2 + i][(nh) * 2 + j] =                                      \
          mfma16(A_[i][1], B_[j][1], acc[(mh) * 2 + i][(nh) * 2 + j]);       \
    }                                                                        \
  __builtin_amdgcn_s_setprio(0);

  const int NT = K >> 6;                    // 16 for K=1024
  // prologue: tiles 0,1 into buffers 0,1
  stage(0, 0); stage(1, 1);
  VMCNT(6);                                 // tile 0 landed (tile 1 in flight)
  BAR();

  int cur = 0, sb = 2;
  for (int t = 0; t < NT; ++t) {
    if (t + 2 < NT) stage(sb, t + 2);       // issue ~2 tiles ahead
    const unsigned short* As_ = lds + cur * BUFS;
    const unsigned short* Bs_ = As_ + 8192;
    bf16x8 a0[2][2], a1[2][2], b0[2][2], b1[2][2];
    LDA(a0, 0); LDB(b0, 0);
    MM(a0, b0, 0, 0);
    LDB(b1, 1);
    MM(a0, b1, 0, 1);
    LDA(a1, 1);
    MM(a1, b1, 1, 1);
    MM(a1, b0, 1, 0);
    if (t + 1 < NT) {
      if (t + 2 < NT) { VMCNT(6); }         // tile t+1 landed; t+2 in flight
      else            { VMCNT(0); }         // drain for the final tiles
      BAR();
    }
    cur = (cur == 2) ? 0 : cur + 1;
    sb = (sb == 2) ? 0 : sb + 1;
  }
#undef LDA
#undef LDB
#undef MM

  // epilogue (wave tile 64 x 64)
#pragma unroll
  for (int mt = 0; mt < 4; ++mt) {
#pragma unroll
    for (int nt = 0; nt < 4; ++nt) {
      int n_g = n0 + wn * 64 + nt * 16 + lr;
      float bv = bias[n_g];
      if (MODE == 1) {
#pragma unroll
        for (int r = 0; r < 4; ++r) {
          int m_g = m0 + wm * 64 + mt * 16 + lq * 4 + r;
          Cf[(size_t)m_g * N + n_g] = acc[mt][nt][r] + bv;
        }
      } else {
        int which = n_g >> 10;               // 0:Q 1:K 2:V (wave-uniform)
        int rem = n_g & 1023;
        int h = rem >> 6, d = rem & 63;
        int m_base = m0 + wm * 64 + mt * 16 + lq * 4;
        int b = m_base >> 11, tt = m_base & 2047;
        if (which == 2) {
          uint2 pv;
          pv.x = cvt_pk_bf16(acc[mt][nt][0] + bv, acc[mt][nt][1] + bv);
          pv.y = cvt_pk_bf16(acc[mt][nt][2] + bv, acc[mt][nt][3] + bv);
          *(uint2*)(Vo + (((size_t)(b * 16 + h) * 64 + d) * 2048 + tt)) = pv;
        } else {
          unsigned short* p = (which == 0) ? Qo : Ko;
#pragma unroll
          for (int r = 0; r < 4; ++r) {
            size_t idx = (((size_t)(b * 16 + h) * 2048) + tt + r) * 64 + d;
            p[idx] = f2bf(acc[mt][nt][r] + bv);
          }
        }
      }
    }
  }
}

// ------- flash attention (causal), S^T formulation, 256-row Q-tiles -------
// (unchanged from round 5 — see notes there)
__global__ __launch_bounds__(512, 2) void attn_kernel(
    const unsigned short* __restrict__ Q, const unsigned short* __restrict__ K,
    const unsigned short* __restrict__ V, unsigned short* __restrict__ Y) {
  constexpr int T = 2048, HD = 64, H = 16;
  __shared__ unsigned short Kt[2][64 * 72];   // K rows [kv][d], pad 8
  __shared__ unsigned short Vt[2][64 * 72];   // V^T    [d][kv], pad 8
  __shared__ unsigned short Pt[8][16 * 72];   // per-wave P, [q][kv]

  const int tid = threadIdx.x;
  const int lane = tid & 63;
  const int w = tid >> 6;                     // 0..7
  const int lr = lane & 15, lq = lane >> 4;
  const int pair = blockIdx.x;                // 0..3
  const int h = blockIdx.y;
  const int b = blockIdx.z;
  const size_t bh = (size_t)(b * H + h) * T * HD;   // also V^T base (64*2048)
  const float SC = 0.125f * 1.44269504089f;   // 1/sqrt(64) * log2(e)

  const int krow = tid >> 3, kcb = (tid & 7) << 3;  // 64 rows x 64 cols tile

  float4 kr, vr;
  auto load_tile = [&](int jt) {
    const int c0 = jt * 64;
    kr = *(const float4*)(K + bh + (size_t)(c0 + krow) * HD + kcb);
    vr = *(const float4*)(V + bh + (size_t)krow * T + c0 + kcb);  // V^T row=d
  };
  auto stage = [&](int buf) {
    *(float4*)(&Kt[buf][krow * 72 + kcb]) = kr;
    *(float4*)(&Vt[buf][krow * 72 + kcb]) = vr;
  };

  load_tile(0);

  for (int phase = 0; phase < 2; ++phase) {
    const int qt = phase ? (7 - pair) : pair;
    const int q0 = qt * 256;
    const int nkv = 4 * (qt + 1);
    const int qw = q0 + w * 32;          // wave's first q-row

    bf16x8 qf[2][2];
#pragma unroll
    for (int qs = 0; qs < 2; ++qs)
#pragma unroll
      for (int kb = 0; kb < 2; ++kb)
        qf[qs][kb] = *(const bf16x8*)(Q + bh + (size_t)(qw + qs * 16 + lr) * HD +
                                      kb * 32 + lq * 8);

    f32x4 o[2][4] = {};
    float mi[2] = {-INFINITY, -INFINITY}, li[2] = {0.f, 0.f};

    stage(0);
    load_tile(1);
    __syncthreads();

    for (int jt = 0; jt < nkv; ++jt) {
      const int c0 = jt * 64;
      const int buf = jt & 1;

      if (c0 <= qw + 31) {               // wave-uniform: else tile fully masked
        // S^T = K Q^T : rows kv, cols q (K frags shared across qs)
        f32x4 s[2][4];
        __builtin_amdgcn_s_setprio(1);
#pragma unroll
        for (int nt = 0; nt < 4; ++nt) {
          bf16x8 kf0 = *(const bf16x8*)(&Kt[buf][(nt * 16 + lr) * 72 + lq * 8]);
          bf16x8 kf1 = *(const bf16x8*)(&Kt[buf][(nt * 16 + lr) * 72 + 32 + lq * 8]);
#pragma unroll
          for (int qs = 0; qs < 2; ++qs) {
            f32x4 z = {};
            z = mfma16(kf0, qf[qs][0], z);
            s[qs][nt] = mfma16(kf1, qf[qs][1], z);
          }
        }
        __builtin_amdgcn_s_setprio(0);
        // causal mask (raw domain), diagonal-adjacent tiles only
        if (c0 + 63 > qw) {
#pragma unroll
          for (int qs = 0; qs < 2; ++qs) {
            int qg = qw + qs * 16 + lr;
#pragma unroll
            for (int nt = 0; nt < 4; ++nt)
#pragma unroll
              for (int r = 0; r < 4; ++r) {
                int kvg = c0 + nt * 16 + lq * 4 + r;
                if (kvg > qg) s[qs][nt][r] = -INFINITY;
              }
          }
        }
        // online softmax (scaled domain), T13 defer-max THR=8
        float mxs[2];
#pragma unroll
        for (int qs = 0; qs < 2; ++qs) {
          float mx = -INFINITY;
#pragma unroll
          for (int nt = 0; nt < 4; ++nt)
            mx = fmaxf(mx, fmaxf(fmaxf(s[qs][nt][0], s[qs][nt][1]),
                                 fmaxf(s[qs][nt][2], s[qs][nt][3])));
          mx = fmaxf(mx, __shfl_xor(mx, 16));
          mx = fmaxf(mx, __shfl_xor(mx, 32));
          mxs[qs] = mx * SC;
        }
        if (!__all((mxs[0] <= mi[0] + 8.f) && (mxs[1] <= mi[1] + 8.f))) {
#pragma unroll
          for (int qs = 0; qs < 2; ++qs) {
            float mnew = fmaxf(mi[qs], mxs[qs]);
            float alpha = __builtin_amdgcn_exp2f(mi[qs] - mnew);
            mi[qs] = mnew;
            li[qs] *= alpha;
#pragma unroll
            for (int nt = 0; nt < 4; ++nt)
#pragma unroll
              for (int r = 0; r < 4; ++r) o[qs][nt][r] *= alpha;
          }
        }
        // P = exp2(s*SC - mi) -> per-wave Pt -> B-frag regs (r3-verified path);
        // one 16-row Pt buffer reused across qs (in-wave LDS ordering).
        bf16x8 pf[2][2];
#pragma unroll
        for (int qs = 0; qs < 2; ++qs) {
          float rs = 0.f;
#pragma unroll
          for (int nt = 0; nt < 4; ++nt) {
            float p0 = __builtin_amdgcn_exp2f(fmaf(s[qs][nt][0], SC, -mi[qs]));
            float p1 = __builtin_amdgcn_exp2f(fmaf(s[qs][nt][1], SC, -mi[qs]));
            float p2 = __builtin_amdgcn_exp2f(fmaf(s[qs][nt][2], SC, -mi[qs]));
            float p3 = __builtin_amdgcn_exp2f(fmaf(s[qs][nt][3], SC, -mi[qs]));
            rs += (p0 + p1) + (p2 + p3);
            uint2 pk;
            pk.x = cvt_pk_bf16(p0, p1);
            pk.y = cvt_pk_bf16(p2, p3);
            *(uint2*)(&Pt[w][lr * 72 + nt * 16 + lq * 4]) = pk;
          }
          li[qs] += rs;                  // per-lane partial; reduced at end
#pragma unroll
          for (int kb = 0; kb < 2; ++kb)
            pf[qs][kb] = *(const bf16x8*)(&Pt[w][lr * 72 + kb * 32 + lq * 8]);
        }
        // O^T += V^T P^T (V frags read once, used for both qs)
        __builtin_amdgcn_s_setprio(1);
#pragma unroll
        for (int nt = 0; nt < 4; ++nt) {
          bf16x8 vf0 = *(const bf16x8*)(&Vt[buf][(nt * 16 + lr) * 72 + lq * 8]);
          bf16x8 vf1 = *(const bf16x8*)(&Vt[buf][(nt * 16 + lr) * 72 + 32 + lq * 8]);
#pragma unroll
          for (int qs = 0; qs < 2; ++qs) {
            o[qs][nt] = mfma16(vf0, pf[qs][0], o[qs][nt]);
            o[qs][nt] = mfma16(vf1, pf[qs][1], o[qs][nt]);
          }
        }
        __builtin_amdgcn_s_setprio(0);
      }

      if (jt + 1 < nkv) {
        stage(buf ^ 1);
        if (jt + 2 < nkv) load_tile(jt + 2);
        else if (phase == 0) load_tile(0);
        __syncthreads();
      }
    }

    // epilogue: reduce per-lane li over lq groups, write Y
#pragma unroll
    for (int qs = 0; qs < 2; ++qs) {
      float l = li[qs];
      l += __shfl_xor(l, 16);
      l += __shfl_xor(l, 32);
      float inv = 1.f / l;
      int t_g = qw + qs * 16 + lr;
#pragma unroll
      for (int nt = 0; nt < 4; ++nt) {
        uint2 yv;
        yv.x = cvt_pk_bf16(o[qs][nt][0] * inv, o[qs][nt][1] * inv);
        yv.y = cvt_pk_bf16(o[qs][nt][2] * inv, o[qs][nt][3] * inv);
        *(uint2*)(Y + ((size_t)(b * T + t_g)) * 1024 + h * 64 + nt * 16 + lq * 4) = yv;
      }
    }
  }
}

// ---------------- launch ----------------
extern "C" void kernel_launch(void* const* d_in, const int* in_sizes, int n_in,
                              void* d_out, int out_size, void* d_ws, size_t ws_size,
                              hipStream_t stream) {
  const float* x = (const float*)d_in[0];       // [4,2048,1024]
  const float* qkv_w = (const float*)d_in[1];   // [3072,1024]
  const float* qkv_b = (const float*)d_in[2];   // [3072]
  const float* proj_w = (const float*)d_in[3];  // [1024,1024]
  const float* proj_b = (const float*)d_in[4];  // [1024]
  float* out = (float*)d_out;                   // [4,2048,1024] fp32

  unsigned short* ws = (unsigned short*)d_ws;
  unsigned short* xb = ws;                     // 8388608
  unsigned short* wqkv = xb + 8388608;         // 3145728
  unsigned short* wproj = wqkv + 3145728;      // 1048576
  unsigned short* Qb = wproj + 1048576;        // 8388608 [B,H,T,hd]
  unsigned short* Kb = Qb + 8388608;           // 8388608 [B,H,T,hd]
  unsigned short* Vb = Kb + 8388608;           // 8388608 [B,H,hd,T] (transposed!)
  unsigned short* Yb = Vb + 8388608;           // 8388608 [B*T, C]

  auto* g0 = gemm8<0>;
  auto* g1 = gemm8<1>;
  static bool attr_set = false;
  if (!attr_set) {
    (void)hipFuncSetAttribute((const void*)g0,
                              hipFuncAttributeMaxDynamicSharedMemorySize, 147456);
    (void)hipFuncSetAttribute((const void*)g1,
                              hipFuncAttributeMaxDynamicSharedMemorySize, 147456);
    attr_set = true;
  }

  cvt3_kernel<<<12288, 256, 0, stream>>>(x, xb, qkv_w, wqkv, proj_w, wproj);

  // QKV: M=8192, N=3072, K=1024, BM=128/BN=256 -> grid 64*12=768 (3 rounds)
  gemm8<0><<<dim3(768), 512, 147456, stream>>>(xb, wqkv, qkv_b, nullptr, Qb, Kb,
                                               Vb, 8192, 3072, 1024, 12);
  attn_kernel<<<dim3(4, 16, 4), 512, 0, stream>>>(Qb, Kb, Vb, Yb);
  // proj: M=8192, N=1024, K=1024 -> grid 64*4=256 (1 exact round)
  gemm8<1><<<dim3(256), 512, 147456, stream>>>(Yb, wproj, proj_b, out, nullptr,
                                               nullptr, nullptr, 8192, 1024, 1024, 4);
}

// Round 10
// 252.460 us; speedup vs baseline: 1.0407x; 1.0407x over previous
//
#include <hip/hip_runtime.h>
#include <stdint.h>
#include <math.h>

#define DEVI __device__ __forceinline__

typedef __attribute__((ext_vector_type(8))) short bf16x8;
typedef __attribute__((ext_vector_type(4))) float f32x4;

DEVI unsigned short f2bf(float f) {
  union { float f; unsigned u; } v; v.f = f;
  unsigned u = v.u;
  u += 0x7fffu + ((u >> 16) & 1u);   // round-to-nearest-even
  return (unsigned short)(u >> 16);
}

// pack two f32 -> one dword of 2x bf16 (lo = a, hi = b), RNE; no builtin on gfx950
DEVI unsigned cvt_pk_bf16(float a, float b) {
  unsigned r;
  asm("v_cvt_pk_bf16_f32 %0, %1, %2" : "=v"(r) : "v"(a), "v"(b));
  return r;
}

DEVI f32x4 mfma16(bf16x8 a, bf16x8 b, f32x4 c) {
  return __builtin_amdgcn_mfma_f32_16x16x32_bf16(a, b, c, 0, 0, 0);
}

// async global->LDS, 16 B per lane; LDS dest = wave-uniform base + lane*16
DEVI void gld16(const unsigned short* g, unsigned short* l) {
  __builtin_amdgcn_global_load_lds(
      (const __attribute__((address_space(1))) unsigned int*)(uintptr_t)g,
      (__attribute__((address_space(3))) unsigned int*)(unsigned int)(uintptr_t)l,
      16, 0, 0);
}

#define VMCNT(n) asm volatile("s_waitcnt vmcnt(" #n ")" ::: "memory")
#define BAR()                              \
  do {                                     \
    __builtin_amdgcn_s_barrier();          \
    __builtin_amdgcn_sched_barrier(0);     \
  } while (0)

template <int N> DEVI void vmcntc() {
  static_assert(N >= 0 && N <= 12, "");
  if constexpr (N == 0) VMCNT(0);
  else if constexpr (N == 3) VMCNT(3);
  else if constexpr (N == 4) VMCNT(4);
  else if constexpr (N == 6) VMCNT(6);
  else if constexpr (N == 8) VMCNT(8);
}

// ---------------- fp32 -> bf16 convert (3 buffers, one launch) ----------------
__global__ __launch_bounds__(256) void cvt3_kernel(
    const float* __restrict__ a, unsigned short* __restrict__ oa,
    const float* __restrict__ b, unsigned short* __restrict__ ob,
    const float* __restrict__ c, unsigned short* __restrict__ oc) {
  int bid = blockIdx.x;
  const float* in; unsigned short* out; int i;
  if (bid < 8192)       { in = a; out = oa; i = bid; }
  else if (bid < 11264) { in = b; out = ob; i = bid - 8192; }
  else                  { in = c; out = oc; i = bid - 11264; }
  int idx = (i * 256 + (int)threadIdx.x) * 4;
  float4 v = *(const float4*)(in + idx);
  unsigned lo = f2bf(v.x) | ((unsigned)f2bf(v.y) << 16);
  unsigned hi = f2bf(v.z) | ((unsigned)f2bf(v.w) << 16);
  uint2 o; o.x = lo; o.y = hi;
  *(uint2*)(out + idx) = o;
}

// ======== quad-buffered GEMM: C[M,N] = A[M,K]*Bw[N,K]^T + bias ========
// Round-10: BM=256, BN=NBH*128, BK=32; 8 waves (2M x 4N), wave tile 128x(NBH*32).
// r9 post-mortem: GEMM is LDS-READ-BW-bound (128KB/CU/tile at wave-tile 64x64 ->
// 30% MfmaUtil ceiling = observed). Fix = big wave tile (reuse) + deep zero-gate
// pipeline, which needs BK=32 to fit: 4 buffers x (16+8*NBH)KB, 3-tile prefetch,
// ONE vmcnt+barrier per K-tile, zero intra-tile gates. Per tile: 8+2*NBH ds_reads
// feed 16*NBH MFMAs (one per acc -> no dep chains); 96KB/CU LDS per 256x256x32.
// r7's BK=32 failure was 8-way conflicts on unswizzled 64B rows; fixed here:
// logical 16B-blk lq of row r stored at physical lq^((r>>1)&3) -> 2 lanes/bank
// (free, m136). Staging: linear gld16 dest + inverse-permuted global column.
// MODE==0 writes Q,K as [b,h,t,d] and V TRANSPOSED as [b,h,d,t].
template <int MODE, int NBH>
__global__ __launch_bounds__(512, 2) void gemm8(
    const unsigned short* __restrict__ A, const unsigned short* __restrict__ Bw,
    const float* __restrict__ bias, float* __restrict__ Cf,
    unsigned short* __restrict__ Qo, unsigned short* __restrict__ Ko,
    unsigned short* __restrict__ Vo, int M, int N, int K, int nbx) {
  extern __shared__ unsigned short lds[];   // 4 x [A 8192 | B 4096*NBH] ushorts
  constexpr int BUFS = 8192 + 4096 * NBH;
  constexpr int LPT = 2 + NBH;              // gld16 per thread per tile
  const int tid = threadIdx.x;
  const int lane = tid & 63;
  const int w = tid >> 6;                   // 0..7
  const int wm = w >> 2, wn = w & 3;
  const int lr = lane & 15, lq = lane >> 4;

  // T1: XCD-aware block swizzle (grid % 8 == 0 for both call sites)
  const int cpx = gridDim.x >> 3;
  const int swz = (blockIdx.x & 7) * cpx + (blockIdx.x >> 3);
  const int bx = swz % nbx, by = swz / nbx;
  const int m0 = by * 256, n0 = bx * (NBH * 128);

  // staging: chunk = 16 rows x 32 cols = 1KB. lane -> (row=l>>2, phys slot=l&3);
  // source fetches LOGICAL blk (l&3)^((l>>3)&3) so linear dest = swizzled store.
  const int srow = lane >> 2;
  const int scol = (((lane & 3) ^ ((lane >> 3) & 3)) << 3);
  const unsigned short* pa = A + (size_t)(m0 + srow) * K + scol;
  const unsigned short* pb = Bw + (size_t)(n0 + srow) * K + scol;

  // fragment-read swizzle: physical blk = lq ^ ((row>>1)&3); all fragment row
  // bases are multiples of 16 -> (row>>1)&3 == (lr>>1)&3 (per-lane constant).
  const int rswz = (lq ^ ((lr >> 1) & 3)) << 3;

  f32x4 acc[8][2 * NBH] = {};

  auto sA = [&](int buf, int kt, int c) {
    gld16(pa + (size_t)(c << 4) * K + kt, lds + buf * BUFS + (c << 9));
  };
  auto sB = [&](int buf, int kt, int c) {
    gld16(pb + (size_t)(c << 4) * K + kt, lds + buf * BUFS + 8192 + (c << 9));
  };
  // whole-tile staging: A 16 chunks (2/wave); B NBH*8 chunks (NBH/wave)
  auto stage = [&](int buf, int t) {
    const int kt = t << 5;
    sA(buf, kt, w); sA(buf, kt, 8 + w);
    sB(buf, kt, w);
    if constexpr (NBH == 2) sB(buf, kt, 8 + w);
  };

  const int NT = K >> 5;                    // 32 for K=1024
  // prologue: tiles 0,1,2 into buffers 0,1,2
  stage(0, 0); stage(1, 1); stage(2, 2);
  vmcntc<2 * LPT>();                        // tile 0 landed (1,2 in flight)
  BAR();

  for (int t = 0; t < NT; ++t) {
    if (t + 3 < NT) stage((t + 3) & 3, t + 3);
    const unsigned short* As_ = lds + (t & 3) * BUFS;
    const unsigned short* Bs_ = As_ + 8192;
    bf16x8 af[8], bf[2 * NBH];
#pragma unroll
    for (int mt = 0; mt < 8; ++mt)
      af[mt] = *(const bf16x8*)(As_ + (wm * 128 + mt * 16 + lr) * 32 + rswz);
#pragma unroll
    for (int nt = 0; nt < 2 * NBH; ++nt)
      bf[nt] = *(const bf16x8*)(Bs_ + (wn * (NBH * 32) + nt * 16 + lr) * 32 + rswz);
    __builtin_amdgcn_s_setprio(1);
#pragma unroll
    for (int mt = 0; mt < 8; ++mt)
#pragma unroll
      for (int nt = 0; nt < 2 * NBH; ++nt)
        acc[mt][nt] = mfma16(af[mt], bf[nt], acc[mt][nt]);
    __builtin_amdgcn_s_setprio(0);
    // gate: tile t+1 landed; tiles t+2,t+3 may stay in flight
    if (t + 1 < NT) {
      if (t + 3 < NT)      vmcntc<2 * LPT>();
      else if (t + 2 < NT) vmcntc<LPT>();
      else                 vmcntc<0>();
      BAR();
    }
  }

  // epilogue (wave tile 128 x NBH*32)
#pragma unroll
  for (int mt = 0; mt < 8; ++mt) {
#pragma unroll
    for (int nt = 0; nt < 2 * NBH; ++nt) {
      int n_g = n0 + wn * (NBH * 32) + nt * 16 + lr;
      float bv = bias[n_g];
      if (MODE == 1) {
#pragma unroll
        for (int r = 0; r < 4; ++r) {
          int m_g = m0 + wm * 128 + mt * 16 + lq * 4 + r;
          Cf[(size_t)m_g * N + n_g] = acc[mt][nt][r] + bv;
        }
      } else {
        int which = n_g >> 10;               // 0:Q 1:K 2:V (wave-uniform)
        int rem = n_g & 1023;
        int h = rem >> 6, d = rem & 63;
        int m_base = m0 + wm * 128 + mt * 16 + lq * 4;
        int b = m_base >> 11, tt = m_base & 2047;
        if (which == 2) {
          uint2 pv;
          pv.x = cvt_pk_bf16(acc[mt][nt][0] + bv, acc[mt][nt][1] + bv);
          pv.y = cvt_pk_bf16(acc[mt][nt][2] + bv, acc[mt][nt][3] + bv);
          *(uint2*)(Vo + (((size_t)(b * 16 + h) * 64 + d) * 2048 + tt)) = pv;
        } else {
          unsigned short* p = (which == 0) ? Qo : Ko;
#pragma unroll
          for (int r = 0; r < 4; ++r) {
            size_t idx = (((size_t)(b * 16 + h) * 2048) + tt + r) * 64 + d;
            p[idx] = f2bf(acc[mt][nt][r] + bv);
          }
        }
      }
    }
  }
}

// ------- flash attention (causal), S^T formulation, 256-row Q-tiles -------
// (unchanged from round 5 — see notes there)
__global__ __launch_bounds__(512, 2) void attn_kernel(
    const unsigned short* __restrict__ Q, const unsigned short* __restrict__ K,
    const unsigned short* __restrict__ V, unsigned short* __restrict__ Y) {
  constexpr int T = 2048, HD = 64, H = 16;
  __shared__ unsigned short Kt[2][64 * 72];   // K rows [kv][d], pad 8
  __shared__ unsigned short Vt[2][64 * 72];   // V^T    [d][kv], pad 8
  __shared__ unsigned short Pt[8][16 * 72];   // per-wave P, [q][kv]

  const int tid = threadIdx.x;
  const int lane = tid & 63;
  const int w = tid >> 6;                     // 0..7
  const int lr = lane & 15, lq = lane >> 4;
  const int pair = blockIdx.x;                // 0..3
  const int h = blockIdx.y;
  const int b = blockIdx.z;
  const size_t bh = (size_t)(b * H + h) * T * HD;   // also V^T base (64*2048)
  const float SC = 0.125f * 1.44269504089f;   // 1/sqrt(64) * log2(e)

  const int krow = tid >> 3, kcb = (tid & 7) << 3;  // 64 rows x 64 cols tile

  float4 kr, vr;
  auto load_tile = [&](int jt) {
    const int c0 = jt * 64;
    kr = *(const float4*)(K + bh + (size_t)(c0 + krow) * HD + kcb);
    vr = *(const float4*)(V + bh + (size_t)krow * T + c0 + kcb);  // V^T row=d
  };
  auto stage = [&](int buf) {
    *(float4*)(&Kt[buf][krow * 72 + kcb]) = kr;
    *(float4*)(&Vt[buf][krow * 72 + kcb]) = vr;
  };

  load_tile(0);

  for (int phase = 0; phase < 2; ++phase) {
    const int qt = phase ? (7 - pair) : pair;
    const int q0 = qt * 256;
    const int nkv = 4 * (qt + 1);
    const int qw = q0 + w * 32;          // wave's first q-row

    bf16x8 qf[2][2];
#pragma unroll
    for (int qs = 0; qs < 2; ++qs)
#pragma unroll
      for (int kb = 0; kb < 2; ++kb)
        qf[qs][kb] = *(const bf16x8*)(Q + bh + (size_t)(qw + qs * 16 + lr) * HD +
                                      kb * 32 + lq * 8);

    f32x4 o[2][4] = {};
    float mi[2] = {-INFINITY, -INFINITY}, li[2] = {0.f, 0.f};

    stage(0);
    load_tile(1);
    __syncthreads();

    for (int jt = 0; jt < nkv; ++jt) {
      const int c0 = jt * 64;
      const int buf = jt & 1;

      if (c0 <= qw + 31) {               // wave-uniform: else tile fully masked
        // S^T = K Q^T : rows kv, cols q (K frags shared across qs)
        f32x4 s[2][4];
        __builtin_amdgcn_s_setprio(1);
#pragma unroll
        for (int nt = 0; nt < 4; ++nt) {
          bf16x8 kf0 = *(const bf16x8*)(&Kt[buf][(nt * 16 + lr) * 72 + lq * 8]);
          bf16x8 kf1 = *(const bf16x8*)(&Kt[buf][(nt * 16 + lr) * 72 + 32 + lq * 8]);
#pragma unroll
          for (int qs = 0; qs < 2; ++qs) {
            f32x4 z = {};
            z = mfma16(kf0, qf[qs][0], z);
            s[qs][nt] = mfma16(kf1, qf[qs][1], z);
          }
        }
        __builtin_amdgcn_s_setprio(0);
        // causal mask (raw domain), diagonal-adjacent tiles only
        if (c0 + 63 > qw) {
#pragma unroll
          for (int qs = 0; qs < 2; ++qs) {
            int qg = qw + qs * 16 + lr;
#pragma unroll
            for (int nt = 0; nt < 4; ++nt)
#pragma unroll
              for (int r = 0; r < 4; ++r) {
                int kvg = c0 + nt * 16 + lq * 4 + r;
                if (kvg > qg) s[qs][nt][r] = -INFINITY;
              }
          }
        }
        // online softmax (scaled domain), T13 defer-max THR=8
        float mxs[2];
#pragma unroll
        for (int qs = 0; qs < 2; ++qs) {
          float mx = -INFINITY;
#pragma unroll
          for (int nt = 0; nt < 4; ++nt)
            mx = fmaxf(mx, fmaxf(fmaxf(s[qs][nt][0], s[qs][nt][1]),
                                 fmaxf(s[qs][nt][2], s[qs][nt][3])));
          mx = fmaxf(mx, __shfl_xor(mx, 16));
          mx = fmaxf(mx, __shfl_xor(mx, 32));
          mxs[qs] = mx * SC;
        }
        if (!__all((mxs[0] <= mi[0] + 8.f) && (mxs[1] <= mi[1] + 8.f))) {
#pragma unroll
          for (int qs = 0; qs < 2; ++qs) {
            float mnew = fmaxf(mi[qs], mxs[qs]);
            float alpha = __builtin_amdgcn_exp2f(mi[qs] - mnew);
            mi[qs] = mnew;
            li[qs] *= alpha;
#pragma unroll
            for (int nt = 0; nt < 4; ++nt)
#pragma unroll
              for (int r = 0; r < 4; ++r) o[qs][nt][r] *= alpha;
          }
        }
        // P = exp2(s*SC - mi) -> per-wave Pt -> B-frag regs (r3-verified path);
        // one 16-row Pt buffer reused across qs (in-wave LDS ordering).
        bf16x8 pf[2][2];
#pragma unroll
        for (int qs = 0; qs < 2; ++qs) {
          float rs = 0.f;
#pragma unroll
          for (int nt = 0; nt < 4; ++nt) {
            float p0 = __builtin_amdgcn_exp2f(fmaf(s[qs][nt][0], SC, -mi[qs]));
            float p1 = __builtin_amdgcn_exp2f(fmaf(s[qs][nt][1], SC, -mi[qs]));
            float p2 = __builtin_amdgcn_exp2f(fmaf(s[qs][nt][2], SC, -mi[qs]));
            float p3 = __builtin_amdgcn_exp2f(fmaf(s[qs][nt][3], SC, -mi[qs]));
            rs += (p0 + p1) + (p2 + p3);
            uint2 pk;
            pk.x = cvt_pk_bf16(p0, p1);
            pk.y = cvt_pk_bf16(p2, p3);
            *(uint2*)(&Pt[w][lr * 72 + nt * 16 + lq * 4]) = pk;
          }
          li[qs] += rs;                  // per-lane partial; reduced at end
#pragma unroll
          for (int kb = 0; kb < 2; ++kb)
            pf[qs][kb] = *(const bf16x8*)(&Pt[w][lr * 72 + kb * 32 + lq * 8]);
        }
        // O^T += V^T P^T (V frags read once, used for both qs)
        __builtin_amdgcn_s_setprio(1);
#pragma unroll
        for (int nt = 0; nt < 4; ++nt) {
          bf16x8 vf0 = *(const bf16x8*)(&Vt[buf][(nt * 16 + lr) * 72 + lq * 8]);
          bf16x8 vf1 = *(const bf16x8*)(&Vt[buf][(nt * 16 + lr) * 72 + 32 + lq * 8]);
#pragma unroll
          for (int qs = 0; qs < 2; ++qs) {
            o[qs][nt] = mfma16(vf0, pf[qs][0], o[qs][nt]);
            o[qs][nt] = mfma16(vf1, pf[qs][1], o[qs][nt]);
          }
        }
        __builtin_amdgcn_s_setprio(0);
      }

      if (jt + 1 < nkv) {
        stage(buf ^ 1);
        if (jt + 2 < nkv) load_tile(jt + 2);
        else if (phase == 0) load_tile(0);
        __syncthreads();
      }
    }

    // epilogue: reduce per-lane li over lq groups, write Y
#pragma unroll
    for (int qs = 0; qs < 2; ++qs) {
      float l = li[qs];
      l += __shfl_xor(l, 16);
      l += __shfl_xor(l, 32);
      float inv = 1.f / l;
      int t_g = qw + qs * 16 + lr;
#pragma unroll
      for (int nt = 0; nt < 4; ++nt) {
        uint2 yv;
        yv.x = cvt_pk_bf16(o[qs][nt][0] * inv, o[qs][nt][1] * inv);
        yv.y = cvt_pk_bf16(o[qs][nt][2] * inv, o[qs][nt][3] * inv);
        *(uint2*)(Y + ((size_t)(b * T + t_g)) * 1024 + h * 64 + nt * 16 + lq * 4) = yv;
      }
    }
  }
}

// ---------------- launch ----------------
extern "C" void kernel_launch(void* const* d_in, const int* in_sizes, int n_in,
                              void* d_out, int out_size, void* d_ws, size_t ws_size,
                              hipStream_t stream) {
  const float* x = (const float*)d_in[0];       // [4,2048,1024]
  const float* qkv_w = (const float*)d_in[1];   // [3072,1024]
  const float* qkv_b = (const float*)d_in[2];   // [3072]
  const float* proj_w = (const float*)d_in[3];  // [1024,1024]
  const float* proj_b = (const float*)d_in[4];  // [1024]
  float* out = (float*)d_out;                   // [4,2048,1024] fp32

  unsigned short* ws = (unsigned short*)d_ws;
  unsigned short* xb = ws;                     // 8388608
  unsigned short* wqkv = xb + 8388608;         // 3145728
  unsigned short* wproj = wqkv + 3145728;      // 1048576
  unsigned short* Qb = wproj + 1048576;        // 8388608 [B,H,T,hd]
  unsigned short* Kb = Qb + 8388608;           // 8388608 [B,H,T,hd]
  unsigned short* Vb = Kb + 8388608;           // 8388608 [B,H,hd,T] (transposed!)
  unsigned short* Yb = Vb + 8388608;           // 8388608 [B*T, C]

  auto* g0 = gemm8<0, 2>;
  auto* g1 = gemm8<1, 1>;
  static bool attr_set = false;
  if (!attr_set) {
    (void)hipFuncSetAttribute((const void*)g0,
                              hipFuncAttributeMaxDynamicSharedMemorySize, 131072);
    (void)hipFuncSetAttribute((const void*)g1,
                              hipFuncAttributeMaxDynamicSharedMemorySize, 98304);
    attr_set = true;
  }

  cvt3_kernel<<<12288, 256, 0, stream>>>(x, xb, qkv_w, wqkv, proj_w, wproj);

  // QKV: M=8192, N=3072, K=1024, BM=256/BN=256 -> grid 12*32=384 (384%8==0)
  gemm8<0, 2><<<dim3(384), 512, 131072, stream>>>(xb, wqkv, qkv_b, nullptr, Qb, Kb,
                                                  Vb, 8192, 3072, 1024, 12);
  attn_kernel<<<dim3(4, 16, 4), 512, 0, stream>>>(Qb, Kb, Vb, Yb);
  // proj: M=8192, N=1024, K=1024, BM=256/BN=128 -> grid 8*32=256 (full GPU)
  gemm8<1, 1><<<dim3(256), 512, 98304, stream>>>(Yb, wproj, proj_b, out, nullptr,
                                                 nullptr, nullptr, 8192, 1024, 1024, 8);
}

// Round 11
// 247.416 us; speedup vs baseline: 1.0620x; 1.0204x over previous
//
#include <hip/hip_runtime.h>
#include <stdint.h>
#include <math.h>

#define DEVI __device__ __forceinline__

typedef __attribute__((ext_vector_type(8))) short bf16x8;
typedef __attribute__((ext_vector_type(4))) float f32x4;

DEVI unsigned short f2bf(float f) {
  union { float f; unsigned u; } v; v.f = f;
  unsigned u = v.u;
  u += 0x7fffu + ((u >> 16) & 1u);   // round-to-nearest-even
  return (unsigned short)(u >> 16);
}

// pack two f32 -> one dword of 2x bf16 (lo = a, hi = b), RNE; no builtin on gfx950
DEVI unsigned cvt_pk_bf16(float a, float b) {
  unsigned r;
  asm("v_cvt_pk_bf16_f32 %0, %1, %2" : "=v"(r) : "v"(a), "v"(b));
  return r;
}

DEVI f32x4 mfma16(bf16x8 a, bf16x8 b, f32x4 c) {
  return __builtin_amdgcn_mfma_f32_16x16x32_bf16(a, b, c, 0, 0, 0);
}

// async global->LDS, 16 B per lane; LDS dest = wave-uniform base + lane*16
DEVI void gld16(const unsigned short* g, unsigned short* l) {
  __builtin_amdgcn_global_load_lds(
      (const __attribute__((address_space(1))) unsigned int*)(uintptr_t)g,
      (__attribute__((address_space(3))) unsigned int*)(unsigned int)(uintptr_t)l,
      16, 0, 0);
}

#define VMCNT(n) asm volatile("s_waitcnt vmcnt(" #n ")" ::: "memory")
#define BAR()                              \
  do {                                     \
    __builtin_amdgcn_sched_barrier(0);     \
    __builtin_amdgcn_s_barrier();          \
    __builtin_amdgcn_sched_barrier(0);     \
  } while (0)

template <int N> DEVI void vmcntc() {
  static_assert(N >= 0 && N <= 8, "");
  if constexpr (N == 0) VMCNT(0);
  else if constexpr (N == 3) VMCNT(3);
  else if constexpr (N == 4) VMCNT(4);
}

// ---------------- fp32 -> bf16 convert (3 buffers, one launch) ----------------
__global__ __launch_bounds__(256) void cvt3_kernel(
    const float* __restrict__ a, unsigned short* __restrict__ oa,
    const float* __restrict__ b, unsigned short* __restrict__ ob,
    const float* __restrict__ c, unsigned short* __restrict__ oc) {
  int bid = blockIdx.x;
  const float* in; unsigned short* out; int i;
  if (bid < 8192)       { in = a; out = oa; i = bid; }
  else if (bid < 11264) { in = b; out = ob; i = bid - 8192; }
  else                  { in = c; out = oc; i = bid - 11264; }
  int idx = (i * 256 + (int)threadIdx.x) * 4;
  float4 v = *(const float4*)(in + idx);
  unsigned lo = f2bf(v.x) | ((unsigned)f2bf(v.y) << 16);
  unsigned hi = f2bf(v.z) | ((unsigned)f2bf(v.w) << 16);
  uint2 o; o.x = lo; o.y = hi;
  *(uint2*)(out + idx) = o;
}

// ======== 8-phase GEMM (m201-template port): C = A*Bw^T + bias ========
// Round-11: faithful 8-phase schedule. BM=256, BN=NBH*128, BK=64; 8 waves
// (2M x 4N), wave tile 128 x (NBH*32); LDS 2 buf (tile parity) x
// [A 32KB | B NBH*16KB]. Per 2 K-tiles: 8 phases, each = {stage ONE unit
// (2 gld16 A / NBH gld16 B) ; ds_read this quadrant's new frags ; barrier ;
// MFMA quadrant x K=64 ; barrier}; quadrants (0,0),(0,1),(1,1),(1,0) with
// fragment reuse. vmcnt(2+NBH) ONLY at phases 4 and 8 (derived ledger;
// retires through the units the next 4 phases read). Stage->read distance
// 4-7 phases. WAR: every region re-staged >=1 barrier-sealed phase after
// its last LDS read (audited). r6-verified XOR swizzle (0 conflicts).
// MODE==0 writes Q,K as [b,h,t,d] and V TRANSPOSED as [b,h,d,t].
template <int MODE, int NBH>
__global__ __launch_bounds__(512, 2) void gemm8(
    const unsigned short* __restrict__ A, const unsigned short* __restrict__ Bw,
    const float* __restrict__ bias, float* __restrict__ Cf,
    unsigned short* __restrict__ Qo, unsigned short* __restrict__ Ko,
    unsigned short* __restrict__ Vo, int M, int N, int K, int nbx) {
  extern __shared__ unsigned short lds[];   // 2 x [A 16384 | B 8192*NBH] ush
  constexpr int BUFS = 16384 + 8192 * NBH;
  constexpr int GATE = 2 + NBH;
  const int tid = threadIdx.x;
  const int lane = tid & 63;
  const int w = tid >> 6;                   // 0..7
  const int wm = w >> 2, wn = w & 3;
  const int lr = lane & 15, lq = lane >> 4;

  // T1: XCD-aware block swizzle (grid % 8 == 0 for both call sites)
  const int cpx = gridDim.x >> 3;
  const int swz = (blockIdx.x & 7) * cpx + (blockIdx.x >> 3);
  const int bx = swz % nbx, by = swz / nbx;
  const int m0 = by * 256, n0 = bx * (NBH * 128);

  // staging source coords (swizzle baked into the per-lane global column)
  const int sr = lane >> 3;                       // 0..7 row within chunk
  const int sc = ((lane & 7) ^ sr) << 3;          // swizzled col element
  const unsigned short* pa = A + (size_t)(m0 + sr) * K + sc;
  const unsigned short* pb = Bw + (size_t)(n0 + sr) * K + sc;

  // fragment-read block swizzle offsets (ushorts); row&7 == lr&7 for all frags
  const int bs0 = (lq ^ (lr & 7)) << 3;
  const int bs1 = ((lq + 4) ^ (lr & 7)) << 3;

  f32x4 acc[8][2 * NBH] = {};

  auto sA = [&](int buf, int kt, int c) {
    gld16(pa + (size_t)(c << 3) * K + kt, lds + buf * BUFS + (c << 9));
  };
  auto sB = [&](int buf, int kt, int c) {
    gld16(pb + (size_t)(c << 3) * K + kt, lds + buf * BUFS + 16384 + (c << 9));
  };
  // units (chunk = 8 rows = 1KB): A_a rows{0-63,128-191}, A_b complement;
  // B_a = nh0 stripes, B_b = nh1 stripes.
  auto sAa = [&](int buf, int kt) { sA(buf, kt, w); sA(buf, kt, 16 + w); };
  auto sAb = [&](int buf, int kt) { sA(buf, kt, 8 + w); sA(buf, kt, 24 + w); };
  auto sBa = [&](int buf, int kt) {
    if constexpr (NBH == 2) {
      int c = (w & 3) + ((w >> 2) << 3);
      sB(buf, kt, c); sB(buf, kt, c + 16);
    } else {
      sB(buf, kt, ((w & 3) << 2) + (w >> 2));
    }
  };
  auto sBb = [&](int buf, int kt) {
    if constexpr (NBH == 2) {
      int c = (w & 3) + ((w >> 2) << 3) + 4;
      sB(buf, kt, c); sB(buf, kt, c + 16);
    } else {
      sB(buf, kt, ((w & 3) << 2) + (w >> 2) + 2);
    }
  };

#define LDA(A_, As_, mh)                                                     \
  _Pragma("unroll") for (int i = 0; i < 4; ++i) {                            \
    int ar = wm * 128 + (mh) * 64 + i * 16 + lr;                             \
    A_[i][0] = *(const bf16x8*)((As_) + ar * 64 + bs0);                      \
    A_[i][1] = *(const bf16x8*)((As_) + ar * 64 + bs1);                      \
  }
#define LDB(B_, Bs_, nh)                                                     \
  _Pragma("unroll") for (int j = 0; j < NBH; ++j) {                          \
    int br = wn * (NBH * 32) + (nh) * (NBH * 16) + j * 16 + lr;              \
    B_[j][0] = *(const bf16x8*)((Bs_) + br * 64 + bs0);                      \
    B_[j][1] = *(const bf16x8*)((Bs_) + br * 64 + bs1);                      \
  }
#define MM(A_, B_, mh, nh)                                                   \
  __builtin_amdgcn_s_setprio(1);                                             \
  _Pragma("unroll") for (int i = 0; i < 4; ++i)                              \
    _Pragma("unroll") for (int j = 0; j < NBH; ++j) {                        \
      acc[(mh) * 4 + i][(nh) * NBH + j] = mfma16(                            \
          A_[i][0], B_[j][0], acc[(mh) * 4 + i][(nh) * NBH + j]);            \
      acc[(mh) * 4 + i][(nh) * NBH + j] = mfma16(                            \
          A_[i][1], B_[j][1], acc[(mh) * 4 + i][(nh) * NBH + j]);            \
    }                                                                        \
  __builtin_amdgcn_s_setprio(0);

  const int NT = K >> 6;                    // 16
  const int NI = NT >> 1;                   // 8 iterations, 2 tiles each
  const unsigned short* As0 = lds;
  const unsigned short* Bs0 = lds + 16384;
  const unsigned short* As1 = lds + BUFS;
  const unsigned short* Bs1 = lds + BUFS + 16384;

  // prologue: tile0 (ph3-6 order), then tile1's A_a, B_b (virtual ph7-8)
  sAa(0, 0); sBb(0, 0); sBa(0, 0); sAb(0, 0);
  sAa(1, 64); sBb(1, 64);
  vmcntc<GATE>();                           // tile-0 units landed
  BAR();

  for (int i = 0; i < NI; ++i) {
    const bool more = (i + 1 < NI);
    const int kt1 = (2 * i + 1) << 6;
    const int kt2 = (2 * i + 2) << 6;
    const int kt3 = (2 * i + 3) << 6;
    bf16x8 af[4][2], b0f[NBH][2], b1f[NBH][2];
    // ph1: quadrant (0,0) tile 2i; stage B_a(2i+1)->b1
    sBa(1, kt1);
    LDA(af, As0, 0); LDB(b0f, Bs0, 0);
    BAR();
    MM(af, b0f, 0, 0);
    BAR();
    // ph2: (0,1); stage A_b(2i+1)->b1; reuse A0
    sAb(1, kt1);
    LDB(b1f, Bs0, 1);
    BAR();
    MM(af, b1f, 0, 1);
    BAR();
    // ph3: (1,1); stage A_a(2i+2)->b0 (A_a(b0) last read ph1); load A1
    if (more) sAa(0, kt2);
    LDA(af, As0, 1);
    BAR();
    MM(af, b1f, 1, 1);
    BAR();
    // ph4: (1,0); stage B_b(2i+2)->b0 (B_b(b0) last read ph2); zero reads
    if (more) sBb(0, kt2);
    MM(af, b0f, 1, 0);
    if (more) { vmcntc<GATE>(); } else { vmcntc<0>(); }   // tile 2i+1 landed
    BAR();
    // ph5: (0,0) tile 2i+1; stage B_a(2i+2)->b0 (B_a(b0) last read ph1)
    if (more) sBa(0, kt2);
    LDA(af, As1, 0); LDB(b0f, Bs1, 0);
    BAR();
    MM(af, b0f, 0, 0);
    BAR();
    // ph6: (0,1); stage A_b(2i+2)->b0 (A_b(b0) last read ph3)
    if (more) sAb(0, kt2);
    LDB(b1f, Bs1, 1);
    BAR();
    MM(af, b1f, 0, 1);
    BAR();
    // ph7: (1,1); stage A_a(2i+3)->b1 (A_a(b1) last read ph5)
    if (more) sAa(1, kt3);
    LDA(af, As1, 1);
    BAR();
    MM(af, b1f, 1, 1);
    BAR();
    // ph8: (1,0); stage B_b(2i+3)->b1 (B_b(b1) last read ph6); zero reads
    if (more) sBb(1, kt3);
    MM(af, b0f, 1, 0);
    if (more) { vmcntc<GATE>(); BAR(); }    // tile 2i+2 units (ph3-6) landed
  }
#undef LDA
#undef LDB
#undef MM

  // epilogue (wave tile 128 x NBH*32)
#pragma unroll
  for (int mt = 0; mt < 8; ++mt) {
#pragma unroll
    for (int nt = 0; nt < 2 * NBH; ++nt) {
      int n_g = n0 + wn * (NBH * 32) + nt * 16 + lr;
      float bv = bias[n_g];
      if (MODE == 1) {
#pragma unroll
        for (int r = 0; r < 4; ++r) {
          int m_g = m0 + wm * 128 + mt * 16 + lq * 4 + r;
          Cf[(size_t)m_g * N + n_g] = acc[mt][nt][r] + bv;
        }
      } else {
        int which = n_g >> 10;               // 0:Q 1:K 2:V (wave-uniform)
        int rem = n_g & 1023;
        int h = rem >> 6, d = rem & 63;
        int m_base = m0 + wm * 128 + mt * 16 + lq * 4;
        int b = m_base >> 11, tt = m_base & 2047;
        if (which == 2) {
          uint2 pv;
          pv.x = cvt_pk_bf16(acc[mt][nt][0] + bv, acc[mt][nt][1] + bv);
          pv.y = cvt_pk_bf16(acc[mt][nt][2] + bv, acc[mt][nt][3] + bv);
          *(uint2*)(Vo + (((size_t)(b * 16 + h) * 64 + d) * 2048 + tt)) = pv;
        } else {
          unsigned short* p = (which == 0) ? Qo : Ko;
#pragma unroll
          for (int r = 0; r < 4; ++r) {
            size_t idx = (((size_t)(b * 16 + h) * 2048) + tt + r) * 64 + d;
            p[idx] = f2bf(acc[mt][nt][r] + bv);
          }
        }
      }
    }
  }
}

// ------- flash attention (causal), S^T formulation, 256-row Q-tiles -------
// (unchanged from round 5 — see notes there)
__global__ __launch_bounds__(512, 2) void attn_kernel(
    const unsigned short* __restrict__ Q, const unsigned short* __restrict__ K,
    const unsigned short* __restrict__ V, unsigned short* __restrict__ Y) {
  constexpr int T = 2048, HD = 64, H = 16;
  __shared__ unsigned short Kt[2][64 * 72];   // K rows [kv][d], pad 8
  __shared__ unsigned short Vt[2][64 * 72];   // V^T    [d][kv], pad 8
  __shared__ unsigned short Pt[8][16 * 72];   // per-wave P, [q][kv]

  const int tid = threadIdx.x;
  const int lane = tid & 63;
  const int w = tid >> 6;                     // 0..7
  const int lr = lane & 15, lq = lane >> 4;
  const int pair = blockIdx.x;                // 0..3
  const int h = blockIdx.y;
  const int b = blockIdx.z;
  const size_t bh = (size_t)(b * H + h) * T * HD;   // also V^T base (64*2048)
  const float SC = 0.125f * 1.44269504089f;   // 1/sqrt(64) * log2(e)

  const int krow = tid >> 3, kcb = (tid & 7) << 3;  // 64 rows x 64 cols tile

  float4 kr, vr;
  auto load_tile = [&](int jt) {
    const int c0 = jt * 64;
    kr = *(const float4*)(K + bh + (size_t)(c0 + krow) * HD + kcb);
    vr = *(const float4*)(V + bh + (size_t)krow * T + c0 + kcb);  // V^T row=d
  };
  auto stage = [&](int buf) {
    *(float4*)(&Kt[buf][krow * 72 + kcb]) = kr;
    *(float4*)(&Vt[buf][krow * 72 + kcb]) = vr;
  };

  load_tile(0);

  for (int phase = 0; phase < 2; ++phase) {
    const int qt = phase ? (7 - pair) : pair;
    const int q0 = qt * 256;
    const int nkv = 4 * (qt + 1);
    const int qw = q0 + w * 32;          // wave's first q-row

    bf16x8 qf[2][2];
#pragma unroll
    for (int qs = 0; qs < 2; ++qs)
#pragma unroll
      for (int kb = 0; kb < 2; ++kb)
        qf[qs][kb] = *(const bf16x8*)(Q + bh + (size_t)(qw + qs * 16 + lr) * HD +
                                      kb * 32 + lq * 8);

    f32x4 o[2][4] = {};
    float mi[2] = {-INFINITY, -INFINITY}, li[2] = {0.f, 0.f};

    stage(0);
    load_tile(1);
    __syncthreads();

    for (int jt = 0; jt < nkv; ++jt) {
      const int c0 = jt * 64;
      const int buf = jt & 1;

      if (c0 <= qw + 31) {               // wave-uniform: else tile fully masked
        // S^T = K Q^T : rows kv, cols q (K frags shared across qs)
        f32x4 s[2][4];
        __builtin_amdgcn_s_setprio(1);
#pragma unroll
        for (int nt = 0; nt < 4; ++nt) {
          bf16x8 kf0 = *(const bf16x8*)(&Kt[buf][(nt * 16 + lr) * 72 + lq * 8]);
          bf16x8 kf1 = *(const bf16x8*)(&Kt[buf][(nt * 16 + lr) * 72 + 32 + lq * 8]);
#pragma unroll
          for (int qs = 0; qs < 2; ++qs) {
            f32x4 z = {};
            z = mfma16(kf0, qf[qs][0], z);
            s[qs][nt] = mfma16(kf1, qf[qs][1], z);
          }
        }
        __builtin_amdgcn_s_setprio(0);
        // causal mask (raw domain), diagonal-adjacent tiles only
        if (c0 + 63 > qw) {
#pragma unroll
          for (int qs = 0; qs < 2; ++qs) {
            int qg = qw + qs * 16 + lr;
#pragma unroll
            for (int nt = 0; nt < 4; ++nt)
#pragma unroll
              for (int r = 0; r < 4; ++r) {
                int kvg = c0 + nt * 16 + lq * 4 + r;
                if (kvg > qg) s[qs][nt][r] = -INFINITY;
              }
          }
        }
        // online softmax (scaled domain), T13 defer-max THR=8
        float mxs[2];
#pragma unroll
        for (int qs = 0; qs < 2; ++qs) {
          float mx = -INFINITY;
#pragma unroll
          for (int nt = 0; nt < 4; ++nt)
            mx = fmaxf(mx, fmaxf(fmaxf(s[qs][nt][0], s[qs][nt][1]),
                                 fmaxf(s[qs][nt][2], s[qs][nt][3])));
          mx = fmaxf(mx, __shfl_xor(mx, 16));
          mx = fmaxf(mx, __shfl_xor(mx, 32));
          mxs[qs] = mx * SC;
        }
        if (!__all((mxs[0] <= mi[0] + 8.f) && (mxs[1] <= mi[1] + 8.f))) {
#pragma unroll
          for (int qs = 0; qs < 2; ++qs) {
            float mnew = fmaxf(mi[qs], mxs[qs]);
            float alpha = __builtin_amdgcn_exp2f(mi[qs] - mnew);
            mi[qs] = mnew;
            li[qs] *= alpha;
#pragma unroll
            for (int nt = 0; nt < 4; ++nt)
#pragma unroll
              for (int r = 0; r < 4; ++r) o[qs][nt][r] *= alpha;
          }
        }
        // P = exp2(s*SC - mi) -> per-wave Pt -> B-frag regs (r3-verified path);
        // one 16-row Pt buffer reused across qs (in-wave LDS ordering).
        bf16x8 pf[2][2];
#pragma unroll
        for (int qs = 0; qs < 2; ++qs) {
          float rs = 0.f;
#pragma unroll
          for (int nt = 0; nt < 4; ++nt) {
            float p0 = __builtin_amdgcn_exp2f(fmaf(s[qs][nt][0], SC, -mi[qs]));
            float p1 = __builtin_amdgcn_exp2f(fmaf(s[qs][nt][1], SC, -mi[qs]));
            float p2 = __builtin_amdgcn_exp2f(fmaf(s[qs][nt][2], SC, -mi[qs]));
            float p3 = __builtin_amdgcn_exp2f(fmaf(s[qs][nt][3], SC, -mi[qs]));
            rs += (p0 + p1) + (p2 + p3);
            uint2 pk;
            pk.x = cvt_pk_bf16(p0, p1);
            pk.y = cvt_pk_bf16(p2, p3);
            *(uint2*)(&Pt[w][lr * 72 + nt * 16 + lq * 4]) = pk;
          }
          li[qs] += rs;                  // per-lane partial; reduced at end
#pragma unroll
          for (int kb = 0; kb < 2; ++kb)
            pf[qs][kb] = *(const bf16x8*)(&Pt[w][lr * 72 + kb * 32 + lq * 8]);
        }
        // O^T += V^T P^T (V frags read once, used for both qs)
        __builtin_amdgcn_s_setprio(1);
#pragma unroll
        for (int nt = 0; nt < 4; ++nt) {
          bf16x8 vf0 = *(const bf16x8*)(&Vt[buf][(nt * 16 + lr) * 72 + lq * 8]);
          bf16x8 vf1 = *(const bf16x8*)(&Vt[buf][(nt * 16 + lr) * 72 + 32 + lq * 8]);
#pragma unroll
          for (int qs = 0; qs < 2; ++qs) {
            o[qs][nt] = mfma16(vf0, pf[qs][0], o[qs][nt]);
            o[qs][nt] = mfma16(vf1, pf[qs][1], o[qs][nt]);
          }
        }
        __builtin_amdgcn_s_setprio(0);
      }

      if (jt + 1 < nkv) {
        stage(buf ^ 1);
        if (jt + 2 < nkv) load_tile(jt + 2);
        else if (phase == 0) load_tile(0);
        __syncthreads();
      }
    }

    // epilogue: reduce per-lane li over lq groups, write Y
#pragma unroll
    for (int qs = 0; qs < 2; ++qs) {
      float l = li[qs];
      l += __shfl_xor(l, 16);
      l += __shfl_xor(l, 32);
      float inv = 1.f / l;
      int t_g = qw + qs * 16 + lr;
#pragma unroll
      for (int nt = 0; nt < 4; ++nt) {
        uint2 yv;
        yv.x = cvt_pk_bf16(o[qs][nt][0] * inv, o[qs][nt][1] * inv);
        yv.y = cvt_pk_bf16(o[qs][nt][2] * inv, o[qs][nt][3] * inv);
        *(uint2*)(Y + ((size_t)(b * T + t_g)) * 1024 + h * 64 + nt * 16 + lq * 4) = yv;
      }
    }
  }
}

// ---------------- launch ----------------
extern "C" void kernel_launch(void* const* d_in, const int* in_sizes, int n_in,
                              void* d_out, int out_size, void* d_ws, size_t ws_size,
                              hipStream_t stream) {
  const float* x = (const float*)d_in[0];       // [4,2048,1024]
  const float* qkv_w = (const float*)d_in[1];   // [3072,1024]
  const float* qkv_b = (const float*)d_in[2];   // [3072]
  const float* proj_w = (const float*)d_in[3];  // [1024,1024]
  const float* proj_b = (const float*)d_in[4];  // [1024]
  float* out = (float*)d_out;                   // [4,2048,1024] fp32

  unsigned short* ws = (unsigned short*)d_ws;
  unsigned short* xb = ws;                     // 8388608
  unsigned short* wqkv = xb + 8388608;         // 3145728
  unsigned short* wproj = wqkv + 3145728;      // 1048576
  unsigned short* Qb = wproj + 1048576;        // 8388608 [B,H,T,hd]
  unsigned short* Kb = Qb + 8388608;           // 8388608 [B,H,T,hd]
  unsigned short* Vb = Kb + 8388608;           // 8388608 [B,H,hd,T] (transposed!)
  unsigned short* Yb = Vb + 8388608;           // 8388608 [B*T, C]

  auto* g0 = gemm8<0, 2>;
  auto* g1 = gemm8<1, 1>;
  static bool attr_set = false;
  if (!attr_set) {
    (void)hipFuncSetAttribute((const void*)g0,
                              hipFuncAttributeMaxDynamicSharedMemorySize, 131072);
    (void)hipFuncSetAttribute((const void*)g1,
                              hipFuncAttributeMaxDynamicSharedMemorySize, 98304);
    attr_set = true;
  }

  cvt3_kernel<<<12288, 256, 0, stream>>>(x, xb, qkv_w, wqkv, proj_w, wproj);

  // QKV: M=8192, N=3072, K=1024, BM=256/BN=256 -> grid 12*32=384 (384%8==0)
  gemm8<0, 2><<<dim3(384), 512, 131072, stream>>>(xb, wqkv, qkv_b, nullptr, Qb, Kb,
                                                  Vb, 8192, 3072, 1024, 12);
  attn_kernel<<<dim3(4, 16, 4), 512, 0, stream>>>(Qb, Kb, Vb, Yb);
  // proj: M=8192, N=1024, K=1024, BM=256/BN=128 -> grid 8*32=256 (full GPU)
  gemm8<1, 1><<<dim3(256), 512, 98304, stream>>>(Yb, wproj, proj_b, out, nullptr,
                                                 nullptr, nullptr, 8192, 1024, 1024, 8);
}

// Round 12
// 239.236 us; speedup vs baseline: 1.0983x; 1.0342x over previous
//
#include <hip/hip_runtime.h>
#include <stdint.h>
#include <math.h>

#define DEVI __device__ __forceinline__

typedef __attribute__((ext_vector_type(8))) short bf16x8;
typedef __attribute__((ext_vector_type(4))) float f32x4;

DEVI unsigned short f2bf(float f) {
  union { float f; unsigned u; } v; v.f = f;
  unsigned u = v.u;
  u += 0x7fffu + ((u >> 16) & 1u);   // round-to-nearest-even
  return (unsigned short)(u >> 16);
}

// pack two f32 -> one dword of 2x bf16 (lo = a, hi = b), RNE; no builtin on gfx950
DEVI unsigned cvt_pk_bf16(float a, float b) {
  unsigned r;
  asm("v_cvt_pk_bf16_f32 %0, %1, %2" : "=v"(r) : "v"(a), "v"(b));
  return r;
}

DEVI f32x4 mfma16(bf16x8 a, bf16x8 b, f32x4 c) {
  return __builtin_amdgcn_mfma_f32_16x16x32_bf16(a, b, c, 0, 0, 0);
}

// async global->LDS, 16 B per lane; LDS dest = wave-uniform base + lane*16
DEVI void gld16(const unsigned short* g, unsigned short* l) {
  __builtin_amdgcn_global_load_lds(
      (const __attribute__((address_space(1))) unsigned int*)(uintptr_t)g,
      (__attribute__((address_space(3))) unsigned int*)(unsigned int)(uintptr_t)l,
      16, 0, 0);
}

#define VMCNT(n) asm volatile("s_waitcnt vmcnt(" #n ")" ::: "memory")
#define BAR()                              \
  do {                                     \
    __builtin_amdgcn_s_barrier();          \
    __builtin_amdgcn_sched_barrier(0);     \
  } while (0)

template <int N> DEVI void vmcntc() {
  static_assert(N >= 0 && N <= 8, "");
  if constexpr (N == 0) VMCNT(0);
  else if constexpr (N == 2) VMCNT(2);
  else if constexpr (N == 3) VMCNT(3);
  else if constexpr (N == 4) VMCNT(4);
}

// ---------------- fp32 -> bf16 convert (3 buffers, one launch) ----------------
__global__ __launch_bounds__(256) void cvt3_kernel(
    const float* __restrict__ a, unsigned short* __restrict__ oa,
    const float* __restrict__ b, unsigned short* __restrict__ ob,
    const float* __restrict__ c, unsigned short* __restrict__ oc) {
  int bid = blockIdx.x;
  const float* in; unsigned short* out; int i;
  if (bid < 8192)       { in = a; out = oa; i = bid; }
  else if (bid < 11264) { in = b; out = ob; i = bid - 8192; }
  else                  { in = c; out = oc; i = bid - 11264; }
  int idx = (i * 256 + (int)threadIdx.x) * 4;
  float4 v = *(const float4*)(in + idx);
  unsigned lo = f2bf(v.x) | ((unsigned)f2bf(v.y) << 16);
  unsigned hi = f2bf(v.z) | ((unsigned)f2bf(v.w) << 16);
  uint2 o; o.x = lo; o.y = hi;
  *(uint2*)(out + idx) = o;
}

// ======== 4-phase GEMM (r6-proven), exact-round grids ========
// Round-12: structure unchanged from r8 (BK=64, XOR swizzle -> 0 conflicts,
// dbuf, 4-phase counted vmcnt, fragment reuse), generalized over the B-split:
// BM=256 fixed; BN = 4*(NTA+NTB)*16; wave tile 128 x (NTA+NTB)*16.
//   QKV: (NTA,NTB)=(2,1) -> BN=192, grid 32x16=512 = TWO EXACT ROUNDS.
//   proj: (1,1) -> BN=128, grid 32x8=256 = ONE EXACT ROUND.
// r11 post-mortem: per-block rate is ~39% MfmaUtil in this structure; the
// visible 28% was dilution by the 1.5-round tail of grid 384. Exact-round
// grids remove the tail (QKV predicted 71 -> ~55us).
// Ledger (per-thread units Aa=2, Ba=NTA, Bb=NTB, Ab=2, FIFO retirement):
//   prologue gate vmcnt(NTB+2); ph1 vmcnt(4); ph2 vmcnt(NTA+2);
//   ph4 vmcnt(NTB+2); peel vmcnt(2), vmcnt(0).
// MODE==0 writes Q,K as [b,h,t,d] and V TRANSPOSED as [b,h,d,t].
template <int MODE, int NTA, int NTB>
__global__ __launch_bounds__(512, 2) void gemm8(
    const unsigned short* __restrict__ A, const unsigned short* __restrict__ Bw,
    const float* __restrict__ bias, float* __restrict__ Cf,
    unsigned short* __restrict__ Qo, unsigned short* __restrict__ Ko,
    unsigned short* __restrict__ Vo, int M, int N, int K, int nbx) {
  constexpr int NTT = NTA + NTB;
  constexpr int WTN = NTT * 16;             // wave N-cols
  constexpr int BN = 4 * WTN;
  constexpr int B_USH = BN * 64;
  constexpr int BUFS = 16384 + B_USH;       // A 32KB + B per buffer (ushorts)
  extern __shared__ unsigned short lds[];
  const int tid = threadIdx.x;
  const int lane = tid & 63;
  const int w = tid >> 6;                   // 0..7
  const int wm = w >> 2, wn = w & 3;
  const int lr = lane & 15, lq = lane >> 4;

  // T1: XCD-aware block swizzle (grid % 8 == 0 for both call sites)
  const int cpx = gridDim.x >> 3;
  const int swz = (blockIdx.x & 7) * cpx + (blockIdx.x >> 3);
  const int bx = swz % nbx, by = swz / nbx;
  const int m0 = by * 256, n0 = bx * BN;

  // staging source coords (swizzle baked into the per-lane global column)
  const int sr = lane >> 3;                       // 0..7 row within chunk
  const int sc = ((lane & 7) ^ sr) << 3;          // swizzled col element
  const unsigned short* pa = A + (size_t)(m0 + sr) * K + sc;
  const unsigned short* pb = Bw + (size_t)(n0 + sr) * K + sc;

  // fragment-read block swizzle offsets (ushorts); row&7 == lr&7 for all frags
  const int bs0 = (lq ^ (lr & 7)) << 3;
  const int bs1 = ((lq + 4) ^ (lr & 7)) << 3;

  f32x4 acc[8][NTT] = {};

  auto sA = [&](int buf, int kt, int c) {
    gld16(pa + (size_t)(c << 3) * K + kt, lds + buf * BUFS + (c << 9));
  };
  auto sB = [&](int buf, int kt, int c) {
    gld16(pb + (size_t)(c << 3) * K + kt, lds + buf * BUFS + 16384 + (c << 9));
  };
  // A units (chunk = 8 rows = 1KB): A_a rows {0-63,128-191}; A_b complement.
  auto sAa = [&](int buf, int kt) { sA(buf, kt, w); sA(buf, kt, 16 + w); };
  auto sAb = [&](int buf, int kt) { sA(buf, kt, 8 + w); sA(buf, kt, 24 + w); };
  // B units: per wn section (WTN rows = NTT*2 chunks), B_a = first NTA*16
  // rows, B_b = remaining NTB*16 rows; split across wave pairs by w>>2.
  auto sBa = [&](int buf, int kt) {
#pragma unroll
    for (int k2 = 0; k2 < NTA; ++k2)
      sB(buf, kt, (w & 3) * NTT * 2 + (w >> 2) * NTA + k2);
  };
  auto sBb = [&](int buf, int kt) {
#pragma unroll
    for (int k2 = 0; k2 < NTB; ++k2)
      sB(buf, kt, (w & 3) * NTT * 2 + NTA * 2 + (w >> 2) * NTB + k2);
  };

#define LDA(A_, mh)                                                          \
  _Pragma("unroll") for (int i = 0; i < 4; ++i) {                            \
    int ar = wm * 128 + (mh) * 64 + i * 16 + lr;                             \
    A_[i][0] = *(const bf16x8*)(As_ + ar * 64 + bs0);                        \
    A_[i][1] = *(const bf16x8*)(As_ + ar * 64 + bs1);                        \
  }
#define LDB(B_, CNT, ntb)                                                    \
  _Pragma("unroll") for (int j = 0; j < (CNT); ++j) {                        \
    int br = wn * WTN + ((ntb) + j) * 16 + lr;                               \
    B_[j][0] = *(const bf16x8*)(Bs_ + br * 64 + bs0);                        \
    B_[j][1] = *(const bf16x8*)(Bs_ + br * 64 + bs1);                        \
  }
#define MM(A_, B_, mh, CNT, ntb)                                             \
  __builtin_amdgcn_s_setprio(1);                                             \
  _Pragma("unroll") for (int i = 0; i < 4; ++i)                              \
    _Pragma("unroll") for (int j = 0; j < (CNT); ++j) {                      \
      acc[(mh) * 4 + i][(ntb) + j] =                                         \
          mfma16(A_[i][0], B_[j][0], acc[(mh) * 4 + i][(ntb) + j]);          \
      acc[(mh) * 4 + i][(ntb) + j] =                                         \
          mfma16(A_[i][1], B_[j][1], acc[(mh) * 4 + i][(ntb) + j]);          \
    }                                                                        \
  __builtin_amdgcn_s_setprio(0);

  // prologue: tile 0 into buf0 (unit order A_a, B_a, B_b, A_b)
  sAa(0, 0); sBa(0, 0); sBb(0, 0); sAb(0, 0);
  vmcntc<NTB + 2>();                 // A_a(0), B_a(0) landed
  BAR();

  const int NT = K >> 6;
  for (int t = 0; t < NT - 1; ++t) {
    const int buf = t & 1, nb = buf ^ 1;
    const int kt = (t + 1) << 6;
    const unsigned short* As_ = lds + buf * BUFS;
    const unsigned short* Bs_ = As_ + 16384;
    bf16x8 af[4][2], baf[NTA][2], bbf[NTB][2];
    // ph1: quadrant (0,a); stage A_a(t+1)
    sAa(nb, kt);
    LDA(af, 0); LDB(baf, NTA, 0);
    MM(af, baf, 0, NTA, 0);
    vmcntc<4>(); BAR();              // B_b(t) landed for all waves
    // ph2: (0,b); stage B_a(t+1); reuse A0
    sBa(nb, kt);
    LDB(bbf, NTB, NTA);
    MM(af, bbf, 0, NTB, NTA);
    vmcntc<NTA + 2>(); BAR();        // A_b(t) landed for all waves
    // ph3: (1,b); stage B_b(t+1); reuse Bb, load A1 (A0 dead)
    sBb(nb, kt);
    LDA(af, 1);
    MM(af, bbf, 1, NTB, NTA);
    // ph4: (1,a); stage A_b(t+1); reuse A1 and Ba — zero ds_reads
    sAb(nb, kt);
    MM(af, baf, 1, NTA, 0);
    vmcntc<NTB + 2>(); BAR();        // A_a(t+1), B_a(t+1) landed
  }
  { // peeled last tile (no staging; same phase order, tighter gates)
    const int buf = (NT - 1) & 1;
    const unsigned short* As_ = lds + buf * BUFS;
    const unsigned short* Bs_ = As_ + 16384;
    bf16x8 af[4][2], baf[NTA][2], bbf[NTB][2];
    LDA(af, 0); LDB(baf, NTA, 0);
    MM(af, baf, 0, NTA, 0);
    vmcntc<2>(); BAR();              // B_b(last) landed
    LDB(bbf, NTB, NTA);
    MM(af, bbf, 0, NTB, NTA);
    vmcntc<0>(); BAR();              // A_b(last) landed
    LDA(af, 1);
    MM(af, bbf, 1, NTB, NTA);
    MM(af, baf, 1, NTA, 0);
  }
#undef LDA
#undef LDB
#undef MM

  // epilogue (wave tile 128 x WTN)
#pragma unroll
  for (int mt = 0; mt < 8; ++mt) {
#pragma unroll
    for (int nt = 0; nt < NTT; ++nt) {
      int n_g = n0 + wn * WTN + nt * 16 + lr;
      float bv = bias[n_g];
      if (MODE == 1) {
#pragma unroll
        for (int r = 0; r < 4; ++r) {
          int m_g = m0 + wm * 128 + mt * 16 + lq * 4 + r;
          Cf[(size_t)m_g * N + n_g] = acc[mt][nt][r] + bv;
        }
      } else {
        int which = n_g >> 10;               // 0:Q 1:K 2:V (wave-uniform)
        int rem = n_g & 1023;
        int h = rem >> 6, d = rem & 63;
        int m_base = m0 + wm * 128 + mt * 16 + lq * 4;
        int b = m_base >> 11, tt = m_base & 2047;
        if (which == 2) {
          uint2 pv;
          pv.x = cvt_pk_bf16(acc[mt][nt][0] + bv, acc[mt][nt][1] + bv);
          pv.y = cvt_pk_bf16(acc[mt][nt][2] + bv, acc[mt][nt][3] + bv);
          *(uint2*)(Vo + (((size_t)(b * 16 + h) * 64 + d) * 2048 + tt)) = pv;
        } else {
          unsigned short* p = (which == 0) ? Qo : Ko;
#pragma unroll
          for (int r = 0; r < 4; ++r) {
            size_t idx = (((size_t)(b * 16 + h) * 2048) + tt + r) * 64 + d;
            p[idx] = f2bf(acc[mt][nt][r] + bv);
          }
        }
      }
    }
  }
}

// ------- flash attention (causal), S^T formulation, 256-row Q-tiles -------
// (unchanged from round 5 — see notes there)
__global__ __launch_bounds__(512, 2) void attn_kernel(
    const unsigned short* __restrict__ Q, const unsigned short* __restrict__ K,
    const unsigned short* __restrict__ V, unsigned short* __restrict__ Y) {
  constexpr int T = 2048, HD = 64, H = 16;
  __shared__ unsigned short Kt[2][64 * 72];   // K rows [kv][d], pad 8
  __shared__ unsigned short Vt[2][64 * 72];   // V^T    [d][kv], pad 8
  __shared__ unsigned short Pt[8][16 * 72];   // per-wave P, [q][kv]

  const int tid = threadIdx.x;
  const int lane = tid & 63;
  const int w = tid >> 6;                     // 0..7
  const int lr = lane & 15, lq = lane >> 4;
  const int pair = blockIdx.x;                // 0..3
  const int h = blockIdx.y;
  const int b = blockIdx.z;
  const size_t bh = (size_t)(b * H + h) * T * HD;   // also V^T base (64*2048)
  const float SC = 0.125f * 1.44269504089f;   // 1/sqrt(64) * log2(e)

  const int krow = tid >> 3, kcb = (tid & 7) << 3;  // 64 rows x 64 cols tile

  float4 kr, vr;
  auto load_tile = [&](int jt) {
    const int c0 = jt * 64;
    kr = *(const float4*)(K + bh + (size_t)(c0 + krow) * HD + kcb);
    vr = *(const float4*)(V + bh + (size_t)krow * T + c0 + kcb);  // V^T row=d
  };
  auto stage = [&](int buf) {
    *(float4*)(&Kt[buf][krow * 72 + kcb]) = kr;
    *(float4*)(&Vt[buf][krow * 72 + kcb]) = vr;
  };

  load_tile(0);

  for (int phase = 0; phase < 2; ++phase) {
    const int qt = phase ? (7 - pair) : pair;
    const int q0 = qt * 256;
    const int nkv = 4 * (qt + 1);
    const int qw = q0 + w * 32;          // wave's first q-row

    bf16x8 qf[2][2];
#pragma unroll
    for (int qs = 0; qs < 2; ++qs)
#pragma unroll
      for (int kb = 0; kb < 2; ++kb)
        qf[qs][kb] = *(const bf16x8*)(Q + bh + (size_t)(qw + qs * 16 + lr) * HD +
                                      kb * 32 + lq * 8);

    f32x4 o[2][4] = {};
    float mi[2] = {-INFINITY, -INFINITY}, li[2] = {0.f, 0.f};

    stage(0);
    load_tile(1);
    __syncthreads();

    for (int jt = 0; jt < nkv; ++jt) {
      const int c0 = jt * 64;
      const int buf = jt & 1;

      if (c0 <= qw + 31) {               // wave-uniform: else tile fully masked
        // S^T = K Q^T : rows kv, cols q (K frags shared across qs)
        f32x4 s[2][4];
        __builtin_amdgcn_s_setprio(1);
#pragma unroll
        for (int nt = 0; nt < 4; ++nt) {
          bf16x8 kf0 = *(const bf16x8*)(&Kt[buf][(nt * 16 + lr) * 72 + lq * 8]);
          bf16x8 kf1 = *(const bf16x8*)(&Kt[buf][(nt * 16 + lr) * 72 + 32 + lq * 8]);
#pragma unroll
          for (int qs = 0; qs < 2; ++qs) {
            f32x4 z = {};
            z = mfma16(kf0, qf[qs][0], z);
            s[qs][nt] = mfma16(kf1, qf[qs][1], z);
          }
        }
        __builtin_amdgcn_s_setprio(0);
        // causal mask (raw domain), diagonal-adjacent tiles only
        if (c0 + 63 > qw) {
#pragma unroll
          for (int qs = 0; qs < 2; ++qs) {
            int qg = qw + qs * 16 + lr;
#pragma unroll
            for (int nt = 0; nt < 4; ++nt)
#pragma unroll
              for (int r = 0; r < 4; ++r) {
                int kvg = c0 + nt * 16 + lq * 4 + r;
                if (kvg > qg) s[qs][nt][r] = -INFINITY;
              }
          }
        }
        // online softmax (scaled domain), T13 defer-max THR=8
        float mxs[2];
#pragma unroll
        for (int qs = 0; qs < 2; ++qs) {
          float mx = -INFINITY;
#pragma unroll
          for (int nt = 0; nt < 4; ++nt)
            mx = fmaxf(mx, fmaxf(fmaxf(s[qs][nt][0], s[qs][nt][1]),
                                 fmaxf(s[qs][nt][2], s[qs][nt][3])));
          mx = fmaxf(mx, __shfl_xor(mx, 16));
          mx = fmaxf(mx, __shfl_xor(mx, 32));
          mxs[qs] = mx * SC;
        }
        if (!__all((mxs[0] <= mi[0] + 8.f) && (mxs[1] <= mi[1] + 8.f))) {
#pragma unroll
          for (int qs = 0; qs < 2; ++qs) {
            float mnew = fmaxf(mi[qs], mxs[qs]);
            float alpha = __builtin_amdgcn_exp2f(mi[qs] - mnew);
            mi[qs] = mnew;
            li[qs] *= alpha;
#pragma unroll
            for (int nt = 0; nt < 4; ++nt)
#pragma unroll
              for (int r = 0; r < 4; ++r) o[qs][nt][r] *= alpha;
          }
        }
        // P = exp2(s*SC - mi) -> per-wave Pt -> B-frag regs (r3-verified path);
        // one 16-row Pt buffer reused across qs (in-wave LDS ordering).
        bf16x8 pf[2][2];
#pragma unroll
        for (int qs = 0; qs < 2; ++qs) {
          float rs = 0.f;
#pragma unroll
          for (int nt = 0; nt < 4; ++nt) {
            float p0 = __builtin_amdgcn_exp2f(fmaf(s[qs][nt][0], SC, -mi[qs]));
            float p1 = __builtin_amdgcn_exp2f(fmaf(s[qs][nt][1], SC, -mi[qs]));
            float p2 = __builtin_amdgcn_exp2f(fmaf(s[qs][nt][2], SC, -mi[qs]));
            float p3 = __builtin_amdgcn_exp2f(fmaf(s[qs][nt][3], SC, -mi[qs]));
            rs += (p0 + p1) + (p2 + p3);
            uint2 pk;
            pk.x = cvt_pk_bf16(p0, p1);
            pk.y = cvt_pk_bf16(p2, p3);
            *(uint2*)(&Pt[w][lr * 72 + nt * 16 + lq * 4]) = pk;
          }
          li[qs] += rs;                  // per-lane partial; reduced at end
#pragma unroll
          for (int kb = 0; kb < 2; ++kb)
            pf[qs][kb] = *(const bf16x8*)(&Pt[w][lr * 72 + kb * 32 + lq * 8]);
        }
        // O^T += V^T P^T (V frags read once, used for both qs)
        __builtin_amdgcn_s_setprio(1);
#pragma unroll
        for (int nt = 0; nt < 4; ++nt) {
          bf16x8 vf0 = *(const bf16x8*)(&Vt[buf][(nt * 16 + lr) * 72 + lq * 8]);
          bf16x8 vf1 = *(const bf16x8*)(&Vt[buf][(nt * 16 + lr) * 72 + 32 + lq * 8]);
#pragma unroll
          for (int qs = 0; qs < 2; ++qs) {
            o[qs][nt] = mfma16(vf0, pf[qs][0], o[qs][nt]);
            o[qs][nt] = mfma16(vf1, pf[qs][1], o[qs][nt]);
          }
        }
        __builtin_amdgcn_s_setprio(0);
      }

      if (jt + 1 < nkv) {
        stage(buf ^ 1);
        if (jt + 2 < nkv) load_tile(jt + 2);
        else if (phase == 0) load_tile(0);
        __syncthreads();
      }
    }

    // epilogue: reduce per-lane li over lq groups, write Y
#pragma unroll
    for (int qs = 0; qs < 2; ++qs) {
      float l = li[qs];
      l += __shfl_xor(l, 16);
      l += __shfl_xor(l, 32);
      float inv = 1.f / l;
      int t_g = qw + qs * 16 + lr;
#pragma unroll
      for (int nt = 0; nt < 4; ++nt) {
        uint2 yv;
        yv.x = cvt_pk_bf16(o[qs][nt][0] * inv, o[qs][nt][1] * inv);
        yv.y = cvt_pk_bf16(o[qs][nt][2] * inv, o[qs][nt][3] * inv);
        *(uint2*)(Y + ((size_t)(b * T + t_g)) * 1024 + h * 64 + nt * 16 + lq * 4) = yv;
      }
    }
  }
}

// ---------------- launch ----------------
extern "C" void kernel_launch(void* const* d_in, const int* in_sizes, int n_in,
                              void* d_out, int out_size, void* d_ws, size_t ws_size,
                              hipStream_t stream) {
  const float* x = (const float*)d_in[0];       // [4,2048,1024]
  const float* qkv_w = (const float*)d_in[1];   // [3072,1024]
  const float* qkv_b = (const float*)d_in[2];   // [3072]
  const float* proj_w = (const float*)d_in[3];  // [1024,1024]
  const float* proj_b = (const float*)d_in[4];  // [1024]
  float* out = (float*)d_out;                   // [4,2048,1024] fp32

  unsigned short* ws = (unsigned short*)d_ws;
  unsigned short* xb = ws;                     // 8388608
  unsigned short* wqkv = xb + 8388608;         // 3145728
  unsigned short* wproj = wqkv + 3145728;      // 1048576
  unsigned short* Qb = wproj + 1048576;        // 8388608 [B,H,T,hd]
  unsigned short* Kb = Qb + 8388608;           // 8388608 [B,H,T,hd]
  unsigned short* Vb = Kb + 8388608;           // 8388608 [B,H,hd,T] (transposed!)
  unsigned short* Yb = Vb + 8388608;           // 8388608 [B*T, C]

  auto* g0 = gemm8<0, 2, 1>;
  auto* g1 = gemm8<1, 1, 1>;
  static bool attr_set = false;
  if (!attr_set) {
    (void)hipFuncSetAttribute((const void*)g0,
                              hipFuncAttributeMaxDynamicSharedMemorySize, 114688);
    (void)hipFuncSetAttribute((const void*)g1,
                              hipFuncAttributeMaxDynamicSharedMemorySize, 98304);
    attr_set = true;
  }

  cvt3_kernel<<<12288, 256, 0, stream>>>(x, xb, qkv_w, wqkv, proj_w, wproj);

  // QKV: M=8192, N=3072, K=1024, BM=256/BN=192 -> grid 32*16=512 (2 EXACT rounds)
  gemm8<0, 2, 1><<<dim3(512), 512, 114688, stream>>>(xb, wqkv, qkv_b, nullptr, Qb,
                                                     Kb, Vb, 8192, 3072, 1024, 16);
  attn_kernel<<<dim3(4, 16, 4), 512, 0, stream>>>(Qb, Kb, Vb, Yb);
  // proj: M=8192, N=1024, K=1024, BM=256/BN=128 -> grid 32*8=256 (1 exact round)
  gemm8<1, 1, 1><<<dim3(256), 512, 98304, stream>>>(Yb, wproj, proj_b, out, nullptr,
                                                    nullptr, nullptr, 8192, 1024,
                                                    1024, 8);
}